// Round 1
// baseline (4451.188 us; speedup 1.0000x reference)
//
#include <hip/hip_runtime.h>
#include <cstdint>
#include <cstddef>

// LSTM: IC=HC=512, L=2, T=512, BS=64.  out = [T,64,512] fp32, hs/cs = [2,64,512] fp32.
// R2: single fused sync domain.  64 persistent WGs; each WG owns hidden cols 8wg..8wg+7
//     in BOTH layers (layer1 skewed one step).  Per-producer flag lines (plain atomic
//     stores, no RMW) + wave-parallel ballot polling.  h0(tau-1) fragments shared between
//     layer0 recurrent K-half and layer1 x K-half.  Both weight slices resident in LDS
//     (134 KB, 1 WG/CU).

#define T_STEPS 512
#define WROW 1032   // LDS row stride (bf16 elems): 1024 + 8 pad

typedef float f32x4 __attribute__((ext_vector_type(4)));
typedef short s16x8 __attribute__((ext_vector_type(8)));

__device__ __forceinline__ unsigned short f2bf(float f) {
    unsigned int u = __builtin_bit_cast(unsigned int, f);
    u += 0x7FFFu + ((u >> 16) & 1u);          // round-to-nearest-even
    return (unsigned short)(u >> 16);
}
__device__ __forceinline__ float sig_(float x)  { return 1.0f / (1.0f + __expf(-x)); }
__device__ __forceinline__ float tanh_(float x) { return 1.0f - 2.0f / (__expf(2.0f * x) + 1.0f); }

// Coherent (agent-scope, MALL) 16B load/store as 2x8B relaxed atomics.
__device__ __forceinline__ s16x8 ldc(const unsigned short* p) {
    unsigned long long lo = __hip_atomic_load((unsigned long long*)p,     __ATOMIC_RELAXED, __HIP_MEMORY_SCOPE_AGENT);
    unsigned long long hi = __hip_atomic_load((unsigned long long*)p + 1, __ATOMIC_RELAXED, __HIP_MEMORY_SCOPE_AGENT);
    ulonglong2 u; u.x = lo; u.y = hi;
    return __builtin_bit_cast(s16x8, u);
}
__device__ __forceinline__ void stc(unsigned short* p, s16x8 v) {
    ulonglong2 u = __builtin_bit_cast(ulonglong2, v);
    __hip_atomic_store((unsigned long long*)p,     u.x, __ATOMIC_RELAXED, __HIP_MEMORY_SCOPE_AGENT);
    __hip_atomic_store((unsigned long long*)p + 1, u.y, __ATOMIC_RELAXED, __HIP_MEMORY_SCOPE_AGENT);
}

// ---- prep kernels -------------------------------------------------------

__global__ void k_conv_bf16(const float* __restrict__ src, unsigned short* __restrict__ dst) {
    int i = (blockIdx.x * 256 + threadIdx.x) * 8;
    float4 a = *(const float4*)(src + i);
    float4 b = *(const float4*)(src + i + 4);
    s16x8 o;
    o[0]=(short)f2bf(a.x); o[1]=(short)f2bf(a.y); o[2]=(short)f2bf(a.z); o[3]=(short)f2bf(a.w);
    o[4]=(short)f2bf(b.x); o[5]=(short)f2bf(b.y); o[6]=(short)f2bf(b.z); o[7]=(short)f2bf(b.w);
    *(s16x8*)(dst + i) = o;
}

__global__ void k_transpose_w(const float* __restrict__ W0, const float* __restrict__ W1,
                              unsigned short* __restrict__ WT0, unsigned short* __restrict__ WT1) {
    __shared__ unsigned short tile[32][33];
    const float* W = blockIdx.z ? W1 : W0;
    unsigned short* WT = blockIdx.z ? WT1 : WT0;
    int n0 = blockIdx.x * 32, k0 = blockIdx.y * 32;
    int tx = threadIdx.x, ty = threadIdx.y;       // (32,8)
    #pragma unroll
    for (int i = 0; i < 4; i++)
        tile[ty + i*8][tx] = f2bf(W[(size_t)(k0 + ty + i*8) * 2048 + n0 + tx]);
    __syncthreads();
    #pragma unroll
    for (int i = 0; i < 4; i++)
        WT[(size_t)(n0 + ty + i*8) * 1024 + k0 + tx] = tile[tx][ty + i*8];
}

__global__ void k_hinit(const float* __restrict__ h0, unsigned short* __restrict__ hi0,
                        unsigned short* __restrict__ hi1) {
    int idx = blockIdx.x * 256 + threadIdx.x;   // 65536 total
    int layer = idx >> 15;
    int r = idx & 32767;
    int b = r >> 9;
    int j = r & 511;
    unsigned short v = f2bf(h0[layer * 512 + j]);
    unsigned short* d = layer ? hi1 : hi0;
    d[(size_t)((j >> 3) * 64 + b) * 8 + (j & 7)] = v;
}

// ---- fused persistent recurrence kernel ---------------------------------
// 64 WGs.  WG wg owns hidden cols 8wg..8wg+7 of BOTH layers.
// Iteration tau: layer0 step tau, layer1 step tau-1 (skew 1).  513 iterations.
// h sequences packed [t][jblock(64)][b(64)][8] bf16, coherent (MALL) accesses only.
// Sync: per-WG flag line (plain relaxed store), consumers poll 64 flags via 64 lanes.
__global__ __launch_bounds__(256, 1) void k_lstm_fused2(
    const unsigned short* __restrict__ xb,
    const unsigned short* __restrict__ hi0, const unsigned short* __restrict__ hi1,
    const unsigned short* __restrict__ WT0, const unsigned short* __restrict__ WT1,
    const float* __restrict__ b0, const float* __restrict__ b1,
    const float* __restrict__ c0,
    unsigned short* __restrict__ h0s, unsigned short* __restrict__ h1s,
    float* __restrict__ out, float* __restrict__ hs, float* __restrict__ cs,
    unsigned int* __restrict__ flags)
{
    __shared__ unsigned short Wl[2][32][WROW];   // 132,096 B
    __shared__ unsigned short hst[2][64][8];     //   2,048 B

    const int wg  = (int)blockIdx.x;             // 0..63
    const int tid = (int)threadIdx.x;
    const int j0  = wg * 8;

    // Stage both layers' weight slices: 2 x 32 rows x 1024 bf16, coalesced 16B chunks.
    #pragma unroll
    for (int l = 0; l < 2; l++) {
        const unsigned short* WT = l ? WT1 : WT0;
        #pragma unroll
        for (int it = 0; it < 16; it++) {
            int idx = it * 256 + tid;
            int row = idx >> 7;
            int ch  = idx & 127;
            int gate = (row >> 4) * 2 + ((row & 15) >> 3);    // 0:f 1:i 2:o 3:g
            int gr = gate * 512 + j0 + (row & 7);
            *(s16x8*)(&Wl[l][row][ch * 8]) = *(const s16x8*)(WT + (size_t)gr * 1024 + ch * 8);
        }
    }
    __syncthreads();

    const int lane = tid & 63;
    const int wv   = tid >> 6;
    const int q    = lane >> 4;
    const int cc   = lane & 15;
    const int arow = wv * 16 + cc;
    const int jj   = j0 + (cc & 7);
    const int bb   = wv * 16 + q * 4;

    const float b0t0 = (cc < 8) ? b0[jj] : b0[512 + jj];          // layer0 [f|i]
    const float b0t1 = (cc < 8) ? b0[1024 + jj] : b0[1536 + jj];  // layer0 [o|g]
    const float b1t0 = (cc < 8) ? b1[jj] : b1[512 + jj];
    const float b1t1 = (cc < 8) ? b1[1024 + jj] : b1[1536 + jj];
    float cst0[4], cst1[4];
    { float ci = c0[jj];       cst0[0]=cst0[1]=cst0[2]=cst0[3]=ci; }
    { float ci = c0[512 + jj]; cst1[0]=cst1[1]=cst1[2]=cst1[3]=ci; }

    for (int tau = 0; tau <= T_STEPS; tau++) {
        // x(tau) prefetch: flag-independent, overlaps the poll below.
        s16x8 ax[16];
        if (tau < T_STEPS) {
            const unsigned short* xp = xb + (size_t)(tau * 64 + arow) * 512 + q * 8;
            #pragma unroll
            for (int kk = 0; kk < 16; kk++)
                ax[kk] = *(const s16x8*)(xp + kk * 32);
        }

        // Wait: all 64 producers finished iteration tau-1.
        // Every wave polls independently (lane i watches flag i); no release barrier.
        if (tau > 0) {
            unsigned int tgt = (unsigned int)tau;
            while (true) {
                unsigned int v = __hip_atomic_load(flags + lane * 32, __ATOMIC_RELAXED, __HIP_MEMORY_SCOPE_AGENT);
                if (__ballot(v < tgt) == 0ull) break;
                __builtin_amdgcn_s_sleep(1);
            }
        }

        // h0(tau-1): SHARED input (layer0 recurrent half + layer1 x half).
        s16x8 ah0[16];
        {
            const unsigned short* hb = tau ? (h0s + (size_t)(tau - 1) * 32768) : hi0;
            #pragma unroll
            for (int kk = 0; kk < 16; kk++)
                ah0[kk] = ldc(hb + ((size_t)(kk * 4 + q) * 64 + arow) * 8);
        }
        // h1(tau-2)
        s16x8 ah1[16];
        if (tau > 0) {
            const unsigned short* hb = (tau > 1) ? (h1s + (size_t)(tau - 2) * 32768) : hi1;
            #pragma unroll
            for (int kk = 0; kk < 16; kk++)
                ah1[kk] = ldc(hb + ((size_t)(kk * 4 + q) * 64 + arow) * 8);
        }

        // ---- layer 0, step tau ----
        if (tau < T_STEPS) {
            f32x4 a0  = {b0t0, b0t0, b0t0, b0t0};
            f32x4 a1  = {b0t1, b0t1, b0t1, b0t1};
            f32x4 a0b = {0.f, 0.f, 0.f, 0.f};
            f32x4 a1b = {0.f, 0.f, 0.f, 0.f};
            #pragma unroll
            for (int kk = 0; kk < 16; kk += 2) {       // K 0..511 : x(tau)
                s16x8 w00 = *(const s16x8*)(&Wl[0][cc][kk * 32 + q * 8]);
                s16x8 w10 = *(const s16x8*)(&Wl[0][16 + cc][kk * 32 + q * 8]);
                a0  = __builtin_amdgcn_mfma_f32_16x16x32_bf16(ax[kk], w00, a0, 0, 0, 0);
                a1  = __builtin_amdgcn_mfma_f32_16x16x32_bf16(ax[kk], w10, a1, 0, 0, 0);
                s16x8 w01 = *(const s16x8*)(&Wl[0][cc][(kk + 1) * 32 + q * 8]);
                s16x8 w11 = *(const s16x8*)(&Wl[0][16 + cc][(kk + 1) * 32 + q * 8]);
                a0b = __builtin_amdgcn_mfma_f32_16x16x32_bf16(ax[kk + 1], w01, a0b, 0, 0, 0);
                a1b = __builtin_amdgcn_mfma_f32_16x16x32_bf16(ax[kk + 1], w11, a1b, 0, 0, 0);
            }
            #pragma unroll
            for (int kk = 0; kk < 16; kk += 2) {       // K 512..1023 : h0(tau-1)
                s16x8 w00 = *(const s16x8*)(&Wl[0][cc][(16 + kk) * 32 + q * 8]);
                s16x8 w10 = *(const s16x8*)(&Wl[0][16 + cc][(16 + kk) * 32 + q * 8]);
                a0  = __builtin_amdgcn_mfma_f32_16x16x32_bf16(ah0[kk], w00, a0, 0, 0, 0);
                a1  = __builtin_amdgcn_mfma_f32_16x16x32_bf16(ah0[kk], w10, a1, 0, 0, 0);
                s16x8 w01 = *(const s16x8*)(&Wl[0][cc][(17 + kk) * 32 + q * 8]);
                s16x8 w11 = *(const s16x8*)(&Wl[0][16 + cc][(17 + kk) * 32 + q * 8]);
                a0b = __builtin_amdgcn_mfma_f32_16x16x32_bf16(ah0[kk + 1], w01, a0b, 0, 0, 0);
                a1b = __builtin_amdgcn_mfma_f32_16x16x32_bf16(ah0[kk + 1], w11, a1b, 0, 0, 0);
            }
            a0 = a0 + a0b;
            a1 = a1 + a1b;

            #pragma unroll
            for (int r = 0; r < 4; r++) {
                float z0 = a0[r], z1 = a1[r];
                float p0 = __shfl_xor(z0, 8, 64);
                float p1 = __shfl_xor(z1, 8, 64);
                float zf = (cc < 8) ? z0 : p0;
                float zi = (cc < 8) ? p0 : z0;
                float zo = (cc < 8) ? z1 : p1;
                float zg = (cc < 8) ? p1 : z1;
                float fg = sig_(zf + 1.0f);            // FORGET_BIAS
                float ig = sig_(zi);
                float og = sig_(zo);
                float gg = tanh_(zg);
                float cn = cst0[r] * fg + gg * ig;
                cst0[r] = cn;
                float hv = og * tanh_(cn);
                int b = bb + r;
                if (cc < 8) hst[0][b][cc] = f2bf(hv);
                if (tau == T_STEPS - 1) {
                    if (cc < 8) hs[(size_t)b * 512 + jj] = hv;
                    else        cs[(size_t)b * 512 + jj] = cn;
                }
            }
        }

        // ---- layer 1, step tau-1 ----
        if (tau > 0) {
            const int t1 = tau - 1;
            f32x4 a0  = {b1t0, b1t0, b1t0, b1t0};
            f32x4 a1  = {b1t1, b1t1, b1t1, b1t1};
            f32x4 a0b = {0.f, 0.f, 0.f, 0.f};
            f32x4 a1b = {0.f, 0.f, 0.f, 0.f};
            #pragma unroll
            for (int kk = 0; kk < 16; kk += 2) {       // K 0..511 : x = h0(tau-1)
                s16x8 w00 = *(const s16x8*)(&Wl[1][cc][kk * 32 + q * 8]);
                s16x8 w10 = *(const s16x8*)(&Wl[1][16 + cc][kk * 32 + q * 8]);
                a0  = __builtin_amdgcn_mfma_f32_16x16x32_bf16(ah0[kk], w00, a0, 0, 0, 0);
                a1  = __builtin_amdgcn_mfma_f32_16x16x32_bf16(ah0[kk], w10, a1, 0, 0, 0);
                s16x8 w01 = *(const s16x8*)(&Wl[1][cc][(kk + 1) * 32 + q * 8]);
                s16x8 w11 = *(const s16x8*)(&Wl[1][16 + cc][(kk + 1) * 32 + q * 8]);
                a0b = __builtin_amdgcn_mfma_f32_16x16x32_bf16(ah0[kk + 1], w01, a0b, 0, 0, 0);
                a1b = __builtin_amdgcn_mfma_f32_16x16x32_bf16(ah0[kk + 1], w11, a1b, 0, 0, 0);
            }
            #pragma unroll
            for (int kk = 0; kk < 16; kk += 2) {       // K 512..1023 : h1(tau-2)
                s16x8 w00 = *(const s16x8*)(&Wl[1][cc][(16 + kk) * 32 + q * 8]);
                s16x8 w10 = *(const s16x8*)(&Wl[1][16 + cc][(16 + kk) * 32 + q * 8]);
                a0  = __builtin_amdgcn_mfma_f32_16x16x32_bf16(ah1[kk], w00, a0, 0, 0, 0);
                a1  = __builtin_amdgcn_mfma_f32_16x16x32_bf16(ah1[kk], w10, a1, 0, 0, 0);
                s16x8 w01 = *(const s16x8*)(&Wl[1][cc][(17 + kk) * 32 + q * 8]);
                s16x8 w11 = *(const s16x8*)(&Wl[1][16 + cc][(17 + kk) * 32 + q * 8]);
                a0b = __builtin_amdgcn_mfma_f32_16x16x32_bf16(ah1[kk + 1], w01, a0b, 0, 0, 0);
                a1b = __builtin_amdgcn_mfma_f32_16x16x32_bf16(ah1[kk + 1], w11, a1b, 0, 0, 0);
            }
            a0 = a0 + a0b;
            a1 = a1 + a1b;

            #pragma unroll
            for (int r = 0; r < 4; r++) {
                float z0 = a0[r], z1 = a1[r];
                float p0 = __shfl_xor(z0, 8, 64);
                float p1 = __shfl_xor(z1, 8, 64);
                float zf = (cc < 8) ? z0 : p0;
                float zi = (cc < 8) ? p0 : z0;
                float zo = (cc < 8) ? z1 : p1;
                float zg = (cc < 8) ? p1 : z1;
                float fg = sig_(zf + 1.0f);            // FORGET_BIAS
                float ig = sig_(zi);
                float og = sig_(zo);
                float gg = tanh_(zg);
                float cn = cst1[r] * fg + gg * ig;
                cst1[r] = cn;
                float hv = og * tanh_(cn);
                int b = bb + r;
                if (cc < 8) hst[1][b][cc] = f2bf(hv);
                if (cc >= 8) out[(size_t)(t1 * 64 + b) * 512 + jj] = hv;
                if (t1 == T_STEPS - 1) {
                    if (cc < 8) hs[(size_t)(64 + b) * 512 + jj] = hv;
                    else        cs[(size_t)(64 + b) * 512 + jj] = cn;
                }
            }
        }

        // Wave-local flush of staged h rows -> one wide coherent store per 16B row.
        if (lane < 16) {
            int row = wv * 16 + lane;
            if (tau < T_STEPS)
                stc(h0s + (size_t)tau * 32768 + (size_t)wg * 512 + (size_t)row * 8,
                    *(const s16x8*)(&hst[0][row][0]));
            if (tau > 0)
                stc(h1s + (size_t)(tau - 1) * 32768 + (size_t)wg * 512 + (size_t)row * 8,
                    *(const s16x8*)(&hst[1][row][0]));
        }

        // Arrival: __syncthreads drains all waves' vmcnt (h stores ack'd at the
        // coherence point), then ONE plain relaxed flag store — no RMW, no fences.
        __syncthreads();
        if (tid == 0 && tau < T_STEPS)
            __hip_atomic_store(flags + wg * 32, (unsigned int)(tau + 1),
                               __ATOMIC_RELAXED, __HIP_MEMORY_SCOPE_AGENT);
    }
}

// ---- launch -------------------------------------------------------------

extern "C" void kernel_launch(void* const* d_in, const int* in_sizes, int n_in,
                              void* d_out, int out_size, void* d_ws, size_t ws_size,
                              hipStream_t stream) {
    const float* x  = (const float*)d_in[0];
    const float* W0 = (const float*)d_in[1];
    const float* b0 = (const float*)d_in[2];
    const float* W1 = (const float*)d_in[3];
    const float* b1 = (const float*)d_in[4];
    const float* h0 = (const float*)d_in[5];
    const float* c0 = (const float*)d_in[6];
    float* out = (float*)d_out;

    char* ws = (char*)d_ws;
    unsigned short* xb  = (unsigned short*)(ws);                               // 33,554,432 B
    unsigned short* h0s = (unsigned short*)(ws + 33554432);                    // 33,554,432 B
    unsigned short* h1s = (unsigned short*)(ws + 2 * 33554432);                // 33,554,432 B
    unsigned short* WT0 = (unsigned short*)(ws + 3 * 33554432);                //  4,194,304 B
    unsigned short* WT1 = (unsigned short*)(ws + 3 * 33554432 + 4194304);      //  4,194,304 B
    unsigned short* hi0 = (unsigned short*)(ws + 3 * 33554432 + 2 * 4194304);            // 65,536 B
    unsigned short* hi1 = (unsigned short*)(ws + 3 * 33554432 + 2 * 4194304 + 65536);    // 65,536 B
    unsigned int*   flags = (unsigned int*)(ws + 3 * 33554432 + 2 * 4194304 + 2 * 65536); // 8 KB

    hipMemsetAsync(flags, 0, 8192, stream);
    k_conv_bf16<<<8192, 256, 0, stream>>>(x, xb);
    k_transpose_w<<<dim3(64, 32, 2), dim3(32, 8), 0, stream>>>(W0, W1, WT0, WT1);
    k_hinit<<<256, 256, 0, stream>>>(h0, hi0, hi1);

    float* hs = out + 16777216;            // [2][64][512]
    float* cs = hs + 65536;                // [2][64][512]
    k_lstm_fused2<<<64, 256, 0, stream>>>(xb, hi0, hi1, WT0, WT1, b0, b1, c0,
                                          h0s, h1s, out, hs, cs, flags);
}

// Round 3
// 3732.585 us; speedup vs baseline: 1.1925x; 1.1925x over previous
//
#include <hip/hip_runtime.h>
#include <cstdint>
#include <cstddef>

// LSTM: IC=HC=512, L=2, T=512, BS=64.  out = [T,64,512] fp32, hs/cs = [2,64,512] fp32.
// R4: 128 pipelined WGs (layer0: blocks 0..63, layer1: 64..127), NO extra workspace
//     (R3's 268MB zxT overflowed d_ws -> core dump).
//     (a) layer0 computes x-half (32 MFMAs, bias-init) BEFORE polling for h0(t-1);
//         layer1 computes h1-half before polling for h0(t).  Half the K-reduction
//         moves off the recurrence critical path on both stages.
//     (b) per-WAVE plain-store flags (4 per WG in one 16B chunk) + per-wave
//         s_waitcnt vmcnt(0); NO __syncthreads in the main loop (hst staging is
//         wave-local, Wl read-only).  No RMW counters, no barrier convoy.
//     (c) consumers poll with one 16B line load per lane (min of 4 wave flags),
//         ballot across 64 lanes; out f32 stores after the flag post.

#define T_STEPS 512
#define WROW 1032   // LDS row stride (bf16 elems): 1024 + 8 pad

typedef float f32x4 __attribute__((ext_vector_type(4)));
typedef short s16x8 __attribute__((ext_vector_type(8)));

__device__ __forceinline__ unsigned short f2bf(float f) {
    unsigned int u = __builtin_bit_cast(unsigned int, f);
    u += 0x7FFFu + ((u >> 16) & 1u);          // round-to-nearest-even
    return (unsigned short)(u >> 16);
}
__device__ __forceinline__ float sig_(float x)  { return 1.0f / (1.0f + __expf(-x)); }
__device__ __forceinline__ float tanh_(float x) { return 1.0f - 2.0f / (__expf(2.0f * x) + 1.0f); }

// Coherent (agent-scope, MALL) 16B load/store as 2x8B relaxed atomics.
__device__ __forceinline__ s16x8 ldc(const unsigned short* p) {
    unsigned long long lo = __hip_atomic_load((unsigned long long*)p,     __ATOMIC_RELAXED, __HIP_MEMORY_SCOPE_AGENT);
    unsigned long long hi = __hip_atomic_load((unsigned long long*)p + 1, __ATOMIC_RELAXED, __HIP_MEMORY_SCOPE_AGENT);
    ulonglong2 u; u.x = lo; u.y = hi;
    return __builtin_bit_cast(s16x8, u);
}
__device__ __forceinline__ void stc(unsigned short* p, s16x8 v) {
    ulonglong2 u = __builtin_bit_cast(ulonglong2, v);
    __hip_atomic_store((unsigned long long*)p,     u.x, __ATOMIC_RELAXED, __HIP_MEMORY_SCOPE_AGENT);
    __hip_atomic_store((unsigned long long*)p + 1, u.y, __ATOMIC_RELAXED, __HIP_MEMORY_SCOPE_AGENT);
}
// min of the 4 wave-flags in one 16B chunk
__device__ __forceinline__ unsigned int min4f(const unsigned int* p) {
    unsigned long long a = __hip_atomic_load((const unsigned long long*)p,     __ATOMIC_RELAXED, __HIP_MEMORY_SCOPE_AGENT);
    unsigned long long b = __hip_atomic_load((const unsigned long long*)p + 1, __ATOMIC_RELAXED, __HIP_MEMORY_SCOPE_AGENT);
    unsigned int m0 = (unsigned int)a, m1 = (unsigned int)(a >> 32);
    unsigned int m2 = (unsigned int)b, m3 = (unsigned int)(b >> 32);
    unsigned int x = m0 < m1 ? m0 : m1;
    unsigned int y = m2 < m3 ? m2 : m3;
    return x < y ? x : y;
}

// ---- prep kernels -------------------------------------------------------

__global__ void k_conv_bf16(const float* __restrict__ src, unsigned short* __restrict__ dst) {
    int i = (blockIdx.x * 256 + threadIdx.x) * 8;
    float4 a = *(const float4*)(src + i);
    float4 b = *(const float4*)(src + i + 4);
    s16x8 o;
    o[0]=(short)f2bf(a.x); o[1]=(short)f2bf(a.y); o[2]=(short)f2bf(a.z); o[3]=(short)f2bf(a.w);
    o[4]=(short)f2bf(b.x); o[5]=(short)f2bf(b.y); o[6]=(short)f2bf(b.z); o[7]=(short)f2bf(b.w);
    *(s16x8*)(dst + i) = o;
}

__global__ void k_transpose_w(const float* __restrict__ W0, const float* __restrict__ W1,
                              unsigned short* __restrict__ WT0, unsigned short* __restrict__ WT1) {
    __shared__ unsigned short tile[32][33];
    const float* W = blockIdx.z ? W1 : W0;
    unsigned short* WT = blockIdx.z ? WT1 : WT0;
    int n0 = blockIdx.x * 32, k0 = blockIdx.y * 32;
    int tx = threadIdx.x, ty = threadIdx.y;       // (32,8)
    #pragma unroll
    for (int i = 0; i < 4; i++)
        tile[ty + i*8][tx] = f2bf(W[(size_t)(k0 + ty + i*8) * 2048 + n0 + tx]);
    __syncthreads();
    #pragma unroll
    for (int i = 0; i < 4; i++)
        WT[(size_t)(n0 + ty + i*8) * 1024 + k0 + tx] = tile[tx][ty + i*8];
}

__global__ void k_hinit(const float* __restrict__ h0, unsigned short* __restrict__ hi0,
                        unsigned short* __restrict__ hi1) {
    int idx = blockIdx.x * 256 + threadIdx.x;   // 65536 total
    int layer = idx >> 15;
    int r = idx & 32767;
    int b = r >> 9;
    int j = r & 511;
    unsigned short v = f2bf(h0[layer * 512 + j]);
    unsigned short* d = layer ? hi1 : hi0;
    d[(size_t)((j >> 3) * 64 + b) * 8 + (j & 7)] = v;
}

// ---- fused persistent recurrence kernel ---------------------------------
// blockIdx 0..63 = layer 0, 64..127 = layer 1; wg = blockIdx&63 owns hidden cols 8wg..+7.
// flags: per-WG 128B block, first 16B = the 4 wave flags (value = steps completed).
__global__ __launch_bounds__(256, 1) void k_lstm_fused4(
    const unsigned short* __restrict__ xb,
    const unsigned short* __restrict__ hi0, const unsigned short* __restrict__ hi1,
    const unsigned short* __restrict__ WT0, const unsigned short* __restrict__ WT1,
    const float* __restrict__ b0, const float* __restrict__ b1,
    const float* __restrict__ c0,
    unsigned short* __restrict__ h0s, unsigned short* __restrict__ h1s,
    float* __restrict__ out, float* __restrict__ hs, float* __restrict__ cs,
    unsigned int* __restrict__ flags)
{
    __shared__ unsigned short Wl[32][WROW];
    __shared__ unsigned short hst[64][8];

    const int isl1 = (int)(blockIdx.x >> 6);
    const int wg   = (int)(blockIdx.x & 63);
    const int tid  = (int)threadIdx.x;
    const int j0   = wg * 8;

    {   // stage this layer's full W (K=1024): 32 rows x 1024 bf16
        const unsigned short* WT = isl1 ? WT1 : WT0;
        #pragma unroll
        for (int it = 0; it < 16; it++) {
            int idx = it * 256 + tid;
            int row = idx >> 7;
            int ch  = idx & 127;
            int gate = (row >> 4) * 2 + ((row & 15) >> 3);   // 0:f 1:i 2:o 3:g
            int gr = gate * 512 + j0 + (row & 7);
            *(s16x8*)(&Wl[row][ch * 8]) = *(const s16x8*)(WT + (size_t)gr * 1024 + ch * 8);
        }
    }
    __syncthreads();

    const int lane = tid & 63;
    const int wv   = tid >> 6;
    const int q    = lane >> 4;
    const int cc   = lane & 15;
    const int arow = wv * 16 + cc;
    const int jj   = j0 + (cc & 7);
    const int bb   = wv * 16 + q * 4;

    const float* bias = isl1 ? b1 : b0;
    const float bt0 = (cc < 8) ? bias[jj] : bias[512 + jj];          // [f|i]
    const float bt1 = (cc < 8) ? bias[1024 + jj] : bias[1536 + jj];  // [o|g]
    float cst[4];
    { float ci = c0[isl1 * 512 + jj]; cst[0]=cst[1]=cst[2]=cst[3]=ci; }

    unsigned int* my_flag = flags + (isl1 * 64 + wg) * 32 + wv;

    if (!isl1) {
        // ================= layer 0 =================
        for (int t = 0; t < T_STEPS; t++) {
            // ---- x-half: flag-independent, off the critical path ----
            s16x8 ax[16];
            {
                const unsigned short* xp = xb + (size_t)(t * 64 + arow) * 512 + q * 8;
                #pragma unroll
                for (int kk = 0; kk < 16; kk++)
                    ax[kk] = *(const s16x8*)(xp + kk * 32);
            }
            f32x4 a0  = {bt0, bt0, bt0, bt0};
            f32x4 a1  = {bt1, bt1, bt1, bt1};
            f32x4 a0b = {0.f, 0.f, 0.f, 0.f};
            f32x4 a1b = {0.f, 0.f, 0.f, 0.f};
            #pragma unroll
            for (int kk = 0; kk < 16; kk += 2) {       // K 0..511 : x(t)
                s16x8 w00 = *(const s16x8*)(&Wl[cc][kk * 32 + q * 8]);
                s16x8 w10 = *(const s16x8*)(&Wl[16 + cc][kk * 32 + q * 8]);
                a0  = __builtin_amdgcn_mfma_f32_16x16x32_bf16(ax[kk], w00, a0, 0, 0, 0);
                a1  = __builtin_amdgcn_mfma_f32_16x16x32_bf16(ax[kk], w10, a1, 0, 0, 0);
                s16x8 w01 = *(const s16x8*)(&Wl[cc][(kk + 1) * 32 + q * 8]);
                s16x8 w11 = *(const s16x8*)(&Wl[16 + cc][(kk + 1) * 32 + q * 8]);
                a0b = __builtin_amdgcn_mfma_f32_16x16x32_bf16(ax[kk + 1], w01, a0b, 0, 0, 0);
                a1b = __builtin_amdgcn_mfma_f32_16x16x32_bf16(ax[kk + 1], w11, a1b, 0, 0, 0);
            }

            // ---- wait for h0(t-1) (all 64 layer0 WGs, 4 wave-flags each) ----
            if (t > 0) {
                const unsigned int tgt = (unsigned int)t;
                const unsigned int* fp = flags + lane * 32;
                while (true) {
                    if (__ballot(min4f(fp) < tgt) == 0ull) break;
                    __builtin_amdgcn_s_sleep(1);
                }
            }

            // ---- h-half ----
            s16x8 ah[16];
            {
                const unsigned short* hb = t ? (h0s + (size_t)(t - 1) * 32768) : hi0;
                #pragma unroll
                for (int kk = 0; kk < 16; kk++)
                    ah[kk] = ldc(hb + ((size_t)(kk * 4 + q) * 64 + arow) * 8);
            }
            #pragma unroll
            for (int kk = 0; kk < 16; kk += 2) {       // K 512..1023 : h0(t-1)
                s16x8 w00 = *(const s16x8*)(&Wl[cc][(16 + kk) * 32 + q * 8]);
                s16x8 w10 = *(const s16x8*)(&Wl[16 + cc][(16 + kk) * 32 + q * 8]);
                a0  = __builtin_amdgcn_mfma_f32_16x16x32_bf16(ah[kk], w00, a0, 0, 0, 0);
                a1  = __builtin_amdgcn_mfma_f32_16x16x32_bf16(ah[kk], w10, a1, 0, 0, 0);
                s16x8 w01 = *(const s16x8*)(&Wl[cc][(17 + kk) * 32 + q * 8]);
                s16x8 w11 = *(const s16x8*)(&Wl[16 + cc][(17 + kk) * 32 + q * 8]);
                a0b = __builtin_amdgcn_mfma_f32_16x16x32_bf16(ah[kk + 1], w01, a0b, 0, 0, 0);
                a1b = __builtin_amdgcn_mfma_f32_16x16x32_bf16(ah[kk + 1], w11, a1b, 0, 0, 0);
            }
            a0 = a0 + a0b;
            a1 = a1 + a1b;

            #pragma unroll
            for (int r = 0; r < 4; r++) {
                float z0 = a0[r], z1 = a1[r];
                float p0 = __shfl_xor(z0, 8, 64);
                float p1 = __shfl_xor(z1, 8, 64);
                float zf = (cc < 8) ? z0 : p0;
                float zi = (cc < 8) ? p0 : z0;
                float zo = (cc < 8) ? z1 : p1;
                float zg = (cc < 8) ? p1 : z1;
                float fg = sig_(zf + 1.0f);            // FORGET_BIAS
                float ig = sig_(zi);
                float og = sig_(zo);
                float gg = tanh_(zg);
                float cn = cst[r] * fg + gg * ig;
                cst[r] = cn;
                float hv = og * tanh_(cn);
                int b = bb + r;
                if (cc < 8) hst[b][cc] = f2bf(hv);     // wave-local rows
                if (t == T_STEPS - 1) {
                    if (cc < 8) hs[(size_t)b * 512 + jj] = hv;
                    else        cs[(size_t)b * 512 + jj] = cn;
                }
            }

            // wave-local flush + per-wave flag (no __syncthreads)
            if (lane < 16) {
                int row = wv * 16 + lane;
                stc(h0s + (size_t)t * 32768 + (size_t)wg * 512 + (size_t)row * 8,
                    *(const s16x8*)(&hst[row][0]));
            }
            asm volatile("s_waitcnt vmcnt(0)" ::: "memory");
            if (lane == 0)
                __hip_atomic_store(my_flag, (unsigned int)(t + 1),
                                   __ATOMIC_RELAXED, __HIP_MEMORY_SCOPE_AGENT);
            asm volatile("" ::: "memory");
        }
    } else {
        // ================= layer 1 =================
        for (int t = 0; t < T_STEPS; t++) {
            // ---- own-layer half first: h1(t-1) . W1r ----
            if (t > 0) {
                const unsigned int tgt = (unsigned int)t;
                const unsigned int* fp = flags + (64 + lane) * 32;
                while (true) {
                    if (__ballot(min4f(fp) < tgt) == 0ull) break;
                    __builtin_amdgcn_s_sleep(1);
                }
            }
            s16x8 ah1[16];
            {
                const unsigned short* hb = t ? (h1s + (size_t)(t - 1) * 32768) : hi1;
                #pragma unroll
                for (int kk = 0; kk < 16; kk++)
                    ah1[kk] = ldc(hb + ((size_t)(kk * 4 + q) * 64 + arow) * 8);
            }
            f32x4 a0  = {bt0, bt0, bt0, bt0};
            f32x4 a1  = {bt1, bt1, bt1, bt1};
            f32x4 a0b = {0.f, 0.f, 0.f, 0.f};
            f32x4 a1b = {0.f, 0.f, 0.f, 0.f};
            #pragma unroll
            for (int kk = 0; kk < 16; kk += 2) {       // K 512..1023 : h1(t-1)
                s16x8 w00 = *(const s16x8*)(&Wl[cc][(16 + kk) * 32 + q * 8]);
                s16x8 w10 = *(const s16x8*)(&Wl[16 + cc][(16 + kk) * 32 + q * 8]);
                a0  = __builtin_amdgcn_mfma_f32_16x16x32_bf16(ah1[kk], w00, a0, 0, 0, 0);
                a1  = __builtin_amdgcn_mfma_f32_16x16x32_bf16(ah1[kk], w10, a1, 0, 0, 0);
                s16x8 w01 = *(const s16x8*)(&Wl[cc][(17 + kk) * 32 + q * 8]);
                s16x8 w11 = *(const s16x8*)(&Wl[16 + cc][(17 + kk) * 32 + q * 8]);
                a0b = __builtin_amdgcn_mfma_f32_16x16x32_bf16(ah1[kk + 1], w01, a0b, 0, 0, 0);
                a1b = __builtin_amdgcn_mfma_f32_16x16x32_bf16(ah1[kk + 1], w11, a1b, 0, 0, 0);
            }

            // ---- wait for h0(t) and finish ----
            {
                const unsigned int tgt = (unsigned int)(t + 1);
                const unsigned int* fp = flags + lane * 32;
                while (true) {
                    if (__ballot(min4f(fp) < tgt) == 0ull) break;
                    __builtin_amdgcn_s_sleep(1);
                }
            }
            s16x8 ah0[16];
            {
                const unsigned short* hb = h0s + (size_t)t * 32768;
                #pragma unroll
                for (int kk = 0; kk < 16; kk++)
                    ah0[kk] = ldc(hb + ((size_t)(kk * 4 + q) * 64 + arow) * 8);
            }
            #pragma unroll
            for (int kk = 0; kk < 16; kk += 2) {       // K 0..511 : x = h0(t)
                s16x8 w00 = *(const s16x8*)(&Wl[cc][kk * 32 + q * 8]);
                s16x8 w10 = *(const s16x8*)(&Wl[16 + cc][kk * 32 + q * 8]);
                a0  = __builtin_amdgcn_mfma_f32_16x16x32_bf16(ah0[kk], w00, a0, 0, 0, 0);
                a1  = __builtin_amdgcn_mfma_f32_16x16x32_bf16(ah0[kk], w10, a1, 0, 0, 0);
                s16x8 w01 = *(const s16x8*)(&Wl[cc][(kk + 1) * 32 + q * 8]);
                s16x8 w11 = *(const s16x8*)(&Wl[16 + cc][(kk + 1) * 32 + q * 8]);
                a0b = __builtin_amdgcn_mfma_f32_16x16x32_bf16(ah0[kk + 1], w01, a0b, 0, 0, 0);
                a1b = __builtin_amdgcn_mfma_f32_16x16x32_bf16(ah0[kk + 1], w11, a1b, 0, 0, 0);
            }
            a0 = a0 + a0b;
            a1 = a1 + a1b;

            float ov[4];
            #pragma unroll
            for (int r = 0; r < 4; r++) {
                float z0 = a0[r], z1 = a1[r];
                float p0 = __shfl_xor(z0, 8, 64);
                float p1 = __shfl_xor(z1, 8, 64);
                float zf = (cc < 8) ? z0 : p0;
                float zi = (cc < 8) ? p0 : z0;
                float zo = (cc < 8) ? z1 : p1;
                float zg = (cc < 8) ? p1 : z1;
                float fg = sig_(zf + 1.0f);            // FORGET_BIAS
                float ig = sig_(zi);
                float og = sig_(zo);
                float gg = tanh_(zg);
                float cn = cst[r] * fg + gg * ig;
                cst[r] = cn;
                float hv = og * tanh_(cn);
                ov[r] = hv;
                int b = bb + r;
                if (cc < 8) hst[b][cc] = f2bf(hv);
                if (t == T_STEPS - 1) {
                    if (cc < 8) hs[(size_t)(64 + b) * 512 + jj] = hv;
                    else        cs[(size_t)(64 + b) * 512 + jj] = cn;
                }
            }

            if (lane < 16) {
                int row = wv * 16 + lane;
                stc(h1s + (size_t)t * 32768 + (size_t)wg * 512 + (size_t)row * 8,
                    *(const s16x8*)(&hst[row][0]));
            }
            asm volatile("s_waitcnt vmcnt(0)" ::: "memory");
            if (lane == 0)
                __hip_atomic_store(my_flag, (unsigned int)(t + 1),
                                   __ATOMIC_RELAXED, __HIP_MEMORY_SCOPE_AGENT);
            asm volatile("" ::: "memory");

            // out stores AFTER the flag post (off the critical path)
            if (cc >= 8) {
                #pragma unroll
                for (int r = 0; r < 4; r++)
                    out[((size_t)(t * 64 + bb + r)) * 512 + jj] = ov[r];
            }
        }
    }
}

// ---- launch -------------------------------------------------------------

extern "C" void kernel_launch(void* const* d_in, const int* in_sizes, int n_in,
                              void* d_out, int out_size, void* d_ws, size_t ws_size,
                              hipStream_t stream) {
    const float* x  = (const float*)d_in[0];
    const float* W0 = (const float*)d_in[1];
    const float* b0 = (const float*)d_in[2];
    const float* W1 = (const float*)d_in[3];
    const float* b1 = (const float*)d_in[4];
    const float* h0 = (const float*)d_in[5];
    const float* c0 = (const float*)d_in[6];
    float* out = (float*)d_out;

    char* ws = (char*)d_ws;
    unsigned short* xb  = (unsigned short*)(ws);                               // 33,554,432 B
    unsigned short* h0s = (unsigned short*)(ws + 33554432);                    // 33,554,432 B
    unsigned short* h1s = (unsigned short*)(ws + 2 * 33554432);                // 33,554,432 B
    unsigned short* WT0 = (unsigned short*)(ws + 3 * 33554432);                //  4,194,304 B
    unsigned short* WT1 = (unsigned short*)(ws + 3 * 33554432 + 4194304);      //  4,194,304 B
    unsigned short* hi0 = (unsigned short*)(ws + 3 * 33554432 + 2 * 4194304);            // 65,536 B
    unsigned short* hi1 = (unsigned short*)(ws + 3 * 33554432 + 2 * 4194304 + 65536);    // 65,536 B
    unsigned int*   flags = (unsigned int*)(ws + 3 * 33554432 + 2 * 4194304 + 2 * 65536); // 16 KB

    hipMemsetAsync(flags, 0, 16384, stream);
    k_conv_bf16<<<8192, 256, 0, stream>>>(x, xb);
    k_transpose_w<<<dim3(64, 32, 2), dim3(32, 8), 0, stream>>>(W0, W1, WT0, WT1);
    k_hinit<<<256, 256, 0, stream>>>(h0, hi0, hi1);

    float* hs = out + 16777216;            // [2][64][512]
    float* cs = hs + 65536;                // [2][64][512]
    k_lstm_fused4<<<128, 256, 0, stream>>>(xb, hi0, hi1, WT0, WT1, b0, b1, c0,
                                           h0s, h1s, out, hs, cs, flags);
}

// Round 4
// 2810.204 us; speedup vs baseline: 1.5839x; 1.3282x over previous
//
#include <hip/hip_runtime.h>
#include <cstdint>
#include <cstddef>

// LSTM: IC=HC=512, L=2, T=512, BS=64.  out = [T,64,512] fp32, hs/cs = [2,64,512] fp32.
// R5: FLAG-FREE pipelined recurrence ("data is the flag").
//     h = o*tanh(c) is strictly in (-1,1), so bf16 0x7FC0 (NaN) is unreachable.
//     h0s/h1s are pre-filled with the canary each launch; producers fire-and-forget
//     8B-atomic h stores (no vmcnt drain, no flag store); consumers' fragment loads
//     double as the dependency wait: load 32 u64s, retry while any == canary64.
//     Sweep-1 loads are issued before the independent MFMA half (x-half / h1-half)
//     so first-load latency hides under compute.  128 WGs, R1 topology + math.

#define T_STEPS 512
#define WROW 1032   // LDS row stride (bf16 elems): 1024 + 8 pad
#define CAN64 0x7FC07FC07FC07FC0ULL

typedef float f32x4 __attribute__((ext_vector_type(4)));
typedef short s16x8 __attribute__((ext_vector_type(8)));

__device__ __forceinline__ unsigned short f2bf(float f) {
    unsigned int u = __builtin_bit_cast(unsigned int, f);
    u += 0x7FFFu + ((u >> 16) & 1u);          // round-to-nearest-even
    return (unsigned short)(u >> 16);
}
__device__ __forceinline__ float sig_(float x)  { return 1.0f / (1.0f + __expf(-x)); }
__device__ __forceinline__ float tanh_(float x) { return 1.0f - 2.0f / (__expf(2.0f * x) + 1.0f); }

// Coherent (agent-scope, MALL) 8B atomic load/store primitives.
__device__ __forceinline__ unsigned long long ld8(const unsigned short* p) {
    return __hip_atomic_load((unsigned long long*)p, __ATOMIC_RELAXED, __HIP_MEMORY_SCOPE_AGENT);
}
__device__ __forceinline__ void stc(unsigned short* p, s16x8 v) {
    ulonglong2 u = __builtin_bit_cast(ulonglong2, v);
    __hip_atomic_store((unsigned long long*)p,     u.x, __ATOMIC_RELAXED, __HIP_MEMORY_SCOPE_AGENT);
    __hip_atomic_store((unsigned long long*)p + 1, u.y, __ATOMIC_RELAXED, __HIP_MEMORY_SCOPE_AGENT);
}

// ---- prep kernels -------------------------------------------------------

__global__ void k_conv_bf16(const float* __restrict__ src, unsigned short* __restrict__ dst) {
    int i = (blockIdx.x * 256 + threadIdx.x) * 8;
    float4 a = *(const float4*)(src + i);
    float4 b = *(const float4*)(src + i + 4);
    s16x8 o;
    o[0]=(short)f2bf(a.x); o[1]=(short)f2bf(a.y); o[2]=(short)f2bf(a.z); o[3]=(short)f2bf(a.w);
    o[4]=(short)f2bf(b.x); o[5]=(short)f2bf(b.y); o[6]=(short)f2bf(b.z); o[7]=(short)f2bf(b.w);
    *(s16x8*)(dst + i) = o;
}

__global__ void k_transpose_w(const float* __restrict__ W0, const float* __restrict__ W1,
                              unsigned short* __restrict__ WT0, unsigned short* __restrict__ WT1) {
    __shared__ unsigned short tile[32][33];
    const float* W = blockIdx.z ? W1 : W0;
    unsigned short* WT = blockIdx.z ? WT1 : WT0;
    int n0 = blockIdx.x * 32, k0 = blockIdx.y * 32;
    int tx = threadIdx.x, ty = threadIdx.y;       // (32,8)
    #pragma unroll
    for (int i = 0; i < 4; i++)
        tile[ty + i*8][tx] = f2bf(W[(size_t)(k0 + ty + i*8) * 2048 + n0 + tx]);
    __syncthreads();
    #pragma unroll
    for (int i = 0; i < 4; i++)
        WT[(size_t)(n0 + ty + i*8) * 1024 + k0 + tx] = tile[tx][ty + i*8];
}

__global__ void k_hinit(const float* __restrict__ h0, unsigned short* __restrict__ hi0,
                        unsigned short* __restrict__ hi1) {
    int idx = blockIdx.x * 256 + threadIdx.x;   // 65536 total
    int layer = idx >> 15;
    int r = idx & 32767;
    int b = r >> 9;
    int j = r & 511;
    unsigned short v = f2bf(h0[layer * 512 + j]);
    unsigned short* d = layer ? hi1 : hi0;
    d[(size_t)((j >> 3) * 64 + b) * 8 + (j & 7)] = v;
}

// canary-fill h0s+h1s (64 MB contiguous): 16B per thread
__global__ void k_fill_canary(unsigned long long* __restrict__ dst) {
    size_t i = ((size_t)blockIdx.x * 256 + threadIdx.x) * 2;
    dst[i]     = CAN64;
    dst[i + 1] = CAN64;
}

// ---- fused persistent recurrence kernel ---------------------------------
// blockIdx 0..63 = layer 0, 64..127 = layer 1; wg = blockIdx&63 owns hidden cols 8wg..+7.
// No flags: consumers validate h fragments against the canary and retry.
__global__ __launch_bounds__(256, 1) void k_lstm_fused5(
    const unsigned short* __restrict__ xb,
    const unsigned short* __restrict__ hi0, const unsigned short* __restrict__ hi1,
    const unsigned short* __restrict__ WT0, const unsigned short* __restrict__ WT1,
    const float* __restrict__ b0, const float* __restrict__ b1,
    const float* __restrict__ c0,
    unsigned short* __restrict__ h0s, unsigned short* __restrict__ h1s,
    float* __restrict__ out, float* __restrict__ hs, float* __restrict__ cs)
{
    __shared__ unsigned short Wl[32][WROW];
    __shared__ unsigned short hst[64][8];

    const int isl1 = (int)(blockIdx.x >> 6);
    const int wg   = (int)(blockIdx.x & 63);
    const int tid  = (int)threadIdx.x;
    const int j0   = wg * 8;

    {   // stage this layer's full W (K=1024): 32 rows x 1024 bf16
        const unsigned short* WT = isl1 ? WT1 : WT0;
        #pragma unroll
        for (int it = 0; it < 16; it++) {
            int idx = it * 256 + tid;
            int row = idx >> 7;
            int ch  = idx & 127;
            int gate = (row >> 4) * 2 + ((row & 15) >> 3);   // 0:f 1:i 2:o 3:g
            int gr = gate * 512 + j0 + (row & 7);
            *(s16x8*)(&Wl[row][ch * 8]) = *(const s16x8*)(WT + (size_t)gr * 1024 + ch * 8);
        }
    }
    __syncthreads();

    const int lane = tid & 63;
    const int wv   = tid >> 6;
    const int q    = lane >> 4;
    const int cc   = lane & 15;
    const int arow = wv * 16 + cc;
    const int jj   = j0 + (cc & 7);
    const int bb   = wv * 16 + q * 4;

    const float* bias = isl1 ? b1 : b0;
    const float bt0 = (cc < 8) ? bias[jj] : bias[512 + jj];          // [f|i]
    const float bt1 = (cc < 8) ? bias[1024 + jj] : bias[1536 + jj];  // [o|g]
    float cst[4];
    { float ci = c0[isl1 * 512 + jj]; cst[0]=cst[1]=cst[2]=cst[3]=ci; }

    if (!isl1) {
        // ================= layer 0 =================
        for (int t = 0; t < T_STEPS; t++) {
            // x fragments: pure input, cached path
            s16x8 ax[16];
            {
                const unsigned short* xp = xb + (size_t)(t * 64 + arow) * 512 + q * 8;
                #pragma unroll
                for (int kk = 0; kk < 16; kk++)
                    ax[kk] = *(const s16x8*)(xp + kk * 32);
            }

            // sweep-1 of h0(t-1): loads double as the dependency wait
            s16x8 ah[16];
            const unsigned short* hb = t ? (h0s + (size_t)(t - 1) * 32768) : hi0;
            bool ok = true;
            #pragma unroll
            for (int kk = 0; kk < 16; kk++) {
                const unsigned short* p = hb + ((size_t)(kk * 4 + q) * 64 + arow) * 8;
                unsigned long long lo = ld8(p), hi = ld8(p + 4);
                ok = ok & (lo != CAN64) & (hi != CAN64);
                ulonglong2 u; u.x = lo; u.y = hi;
                ah[kk] = __builtin_bit_cast(s16x8, u);
            }

            // x-half MFMAs overlap sweep-1 latency
            f32x4 a0  = {bt0, bt0, bt0, bt0};
            f32x4 a1  = {bt1, bt1, bt1, bt1};
            f32x4 a0b = {0.f, 0.f, 0.f, 0.f};
            f32x4 a1b = {0.f, 0.f, 0.f, 0.f};
            #pragma unroll
            for (int kk = 0; kk < 16; kk += 2) {       // K 0..511 : x(t)
                s16x8 w00 = *(const s16x8*)(&Wl[cc][kk * 32 + q * 8]);
                s16x8 w10 = *(const s16x8*)(&Wl[16 + cc][kk * 32 + q * 8]);
                a0  = __builtin_amdgcn_mfma_f32_16x16x32_bf16(ax[kk], w00, a0, 0, 0, 0);
                a1  = __builtin_amdgcn_mfma_f32_16x16x32_bf16(ax[kk], w10, a1, 0, 0, 0);
                s16x8 w01 = *(const s16x8*)(&Wl[cc][(kk + 1) * 32 + q * 8]);
                s16x8 w11 = *(const s16x8*)(&Wl[16 + cc][(kk + 1) * 32 + q * 8]);
                a0b = __builtin_amdgcn_mfma_f32_16x16x32_bf16(ax[kk + 1], w01, a0b, 0, 0, 0);
                a1b = __builtin_amdgcn_mfma_f32_16x16x32_bf16(ax[kk + 1], w11, a1b, 0, 0, 0);
            }

            // retry until all fragments fresh (masked, lagging lanes only)
            while (!ok) {
                __builtin_amdgcn_s_sleep(1);
                ok = true;
                #pragma unroll
                for (int kk = 0; kk < 16; kk++) {
                    const unsigned short* p = hb + ((size_t)(kk * 4 + q) * 64 + arow) * 8;
                    unsigned long long lo = ld8(p), hi = ld8(p + 4);
                    ok = ok & (lo != CAN64) & (hi != CAN64);
                    ulonglong2 u; u.x = lo; u.y = hi;
                    ah[kk] = __builtin_bit_cast(s16x8, u);
                }
            }

            #pragma unroll
            for (int kk = 0; kk < 16; kk += 2) {       // K 512..1023 : h0(t-1)
                s16x8 w00 = *(const s16x8*)(&Wl[cc][(16 + kk) * 32 + q * 8]);
                s16x8 w10 = *(const s16x8*)(&Wl[16 + cc][(16 + kk) * 32 + q * 8]);
                a0  = __builtin_amdgcn_mfma_f32_16x16x32_bf16(ah[kk], w00, a0, 0, 0, 0);
                a1  = __builtin_amdgcn_mfma_f32_16x16x32_bf16(ah[kk], w10, a1, 0, 0, 0);
                s16x8 w01 = *(const s16x8*)(&Wl[cc][(17 + kk) * 32 + q * 8]);
                s16x8 w11 = *(const s16x8*)(&Wl[16 + cc][(17 + kk) * 32 + q * 8]);
                a0b = __builtin_amdgcn_mfma_f32_16x16x32_bf16(ah[kk + 1], w01, a0b, 0, 0, 0);
                a1b = __builtin_amdgcn_mfma_f32_16x16x32_bf16(ah[kk + 1], w11, a1b, 0, 0, 0);
            }
            a0 = a0 + a0b;
            a1 = a1 + a1b;

            #pragma unroll
            for (int r = 0; r < 4; r++) {
                float z0 = a0[r], z1 = a1[r];
                float p0 = __shfl_xor(z0, 8, 64);
                float p1 = __shfl_xor(z1, 8, 64);
                float zf = (cc < 8) ? z0 : p0;
                float zi = (cc < 8) ? p0 : z0;
                float zo = (cc < 8) ? z1 : p1;
                float zg = (cc < 8) ? p1 : z1;
                float fg = sig_(zf + 1.0f);            // FORGET_BIAS
                float ig = sig_(zi);
                float og = sig_(zo);
                float gg = tanh_(zg);
                float cn = cst[r] * fg + gg * ig;
                cst[r] = cn;
                float hv = og * tanh_(cn);
                int b = bb + r;
                if (cc < 8) hst[b][cc] = f2bf(hv);     // wave-local rows
                if (t == T_STEPS - 1) {
                    if (cc < 8) hs[(size_t)b * 512 + jj] = hv;
                    else        cs[(size_t)b * 512 + jj] = cn;
                }
            }

            // wave-local flush: fire-and-forget (8B-atomic stores ARE the flag)
            if (lane < 16) {
                int row = wv * 16 + lane;
                stc(h0s + (size_t)t * 32768 + (size_t)wg * 512 + (size_t)row * 8,
                    *(const s16x8*)(&hst[row][0]));
            }
        }
    } else {
        // ================= layer 1 =================
        for (int t = 0; t < T_STEPS; t++) {
            // A) own-layer h1(t-1): sweep + validate (usually instant)
            s16x8 ah1[16];
            const unsigned short* hb1 = t ? (h1s + (size_t)(t - 1) * 32768) : hi1;
            bool ok1 = true;
            #pragma unroll
            for (int kk = 0; kk < 16; kk++) {
                const unsigned short* p = hb1 + ((size_t)(kk * 4 + q) * 64 + arow) * 8;
                unsigned long long lo = ld8(p), hi = ld8(p + 4);
                ok1 = ok1 & (lo != CAN64) & (hi != CAN64);
                ulonglong2 u; u.x = lo; u.y = hi;
                ah1[kk] = __builtin_bit_cast(s16x8, u);
            }
            while (!ok1) {
                __builtin_amdgcn_s_sleep(1);
                ok1 = true;
                #pragma unroll
                for (int kk = 0; kk < 16; kk++) {
                    const unsigned short* p = hb1 + ((size_t)(kk * 4 + q) * 64 + arow) * 8;
                    unsigned long long lo = ld8(p), hi = ld8(p + 4);
                    ok1 = ok1 & (lo != CAN64) & (hi != CAN64);
                    ulonglong2 u; u.x = lo; u.y = hi;
                    ah1[kk] = __builtin_bit_cast(s16x8, u);
                }
            }

            // B) sweep-1 of h0(t) (the fresh dependency): prefetch now
            s16x8 ah0[16];
            const unsigned short* hb0 = h0s + (size_t)t * 32768;
            bool ok0 = true;
            #pragma unroll
            for (int kk = 0; kk < 16; kk++) {
                const unsigned short* p = hb0 + ((size_t)(kk * 4 + q) * 64 + arow) * 8;
                unsigned long long lo = ld8(p), hi = ld8(p + 4);
                ok0 = ok0 & (lo != CAN64) & (hi != CAN64);
                ulonglong2 u; u.x = lo; u.y = hi;
                ah0[kk] = __builtin_bit_cast(s16x8, u);
            }

            // C) h1-half MFMAs overlap the h0 sweep
            f32x4 a0  = {bt0, bt0, bt0, bt0};
            f32x4 a1  = {bt1, bt1, bt1, bt1};
            f32x4 a0b = {0.f, 0.f, 0.f, 0.f};
            f32x4 a1b = {0.f, 0.f, 0.f, 0.f};
            #pragma unroll
            for (int kk = 0; kk < 16; kk += 2) {       // K 512..1023 : h1(t-1)
                s16x8 w00 = *(const s16x8*)(&Wl[cc][(16 + kk) * 32 + q * 8]);
                s16x8 w10 = *(const s16x8*)(&Wl[16 + cc][(16 + kk) * 32 + q * 8]);
                a0  = __builtin_amdgcn_mfma_f32_16x16x32_bf16(ah1[kk], w00, a0, 0, 0, 0);
                a1  = __builtin_amdgcn_mfma_f32_16x16x32_bf16(ah1[kk], w10, a1, 0, 0, 0);
                s16x8 w01 = *(const s16x8*)(&Wl[cc][(17 + kk) * 32 + q * 8]);
                s16x8 w11 = *(const s16x8*)(&Wl[16 + cc][(17 + kk) * 32 + q * 8]);
                a0b = __builtin_amdgcn_mfma_f32_16x16x32_bf16(ah1[kk + 1], w01, a0b, 0, 0, 0);
                a1b = __builtin_amdgcn_mfma_f32_16x16x32_bf16(ah1[kk + 1], w11, a1b, 0, 0, 0);
            }

            // D) retry h0(t) until fresh
            while (!ok0) {
                __builtin_amdgcn_s_sleep(1);
                ok0 = true;
                #pragma unroll
                for (int kk = 0; kk < 16; kk++) {
                    const unsigned short* p = hb0 + ((size_t)(kk * 4 + q) * 64 + arow) * 8;
                    unsigned long long lo = ld8(p), hi = ld8(p + 4);
                    ok0 = ok0 & (lo != CAN64) & (hi != CAN64);
                    ulonglong2 u; u.x = lo; u.y = hi;
                    ah0[kk] = __builtin_bit_cast(s16x8, u);
                }
            }

            #pragma unroll
            for (int kk = 0; kk < 16; kk += 2) {       // K 0..511 : x = h0(t)
                s16x8 w00 = *(const s16x8*)(&Wl[cc][kk * 32 + q * 8]);
                s16x8 w10 = *(const s16x8*)(&Wl[16 + cc][kk * 32 + q * 8]);
                a0  = __builtin_amdgcn_mfma_f32_16x16x32_bf16(ah0[kk], w00, a0, 0, 0, 0);
                a1  = __builtin_amdgcn_mfma_f32_16x16x32_bf16(ah0[kk], w10, a1, 0, 0, 0);
                s16x8 w01 = *(const s16x8*)(&Wl[cc][(kk + 1) * 32 + q * 8]);
                s16x8 w11 = *(const s16x8*)(&Wl[16 + cc][(kk + 1) * 32 + q * 8]);
                a0b = __builtin_amdgcn_mfma_f32_16x16x32_bf16(ah0[kk + 1], w01, a0b, 0, 0, 0);
                a1b = __builtin_amdgcn_mfma_f32_16x16x32_bf16(ah0[kk + 1], w11, a1b, 0, 0, 0);
            }
            a0 = a0 + a0b;
            a1 = a1 + a1b;

            float ov[4];
            #pragma unroll
            for (int r = 0; r < 4; r++) {
                float z0 = a0[r], z1 = a1[r];
                float p0 = __shfl_xor(z0, 8, 64);
                float p1 = __shfl_xor(z1, 8, 64);
                float zf = (cc < 8) ? z0 : p0;
                float zi = (cc < 8) ? p0 : z0;
                float zo = (cc < 8) ? z1 : p1;
                float zg = (cc < 8) ? p1 : z1;
                float fg = sig_(zf + 1.0f);            // FORGET_BIAS
                float ig = sig_(zi);
                float og = sig_(zo);
                float gg = tanh_(zg);
                float cn = cst[r] * fg + gg * ig;
                cst[r] = cn;
                float hv = og * tanh_(cn);
                ov[r] = hv;
                int b = bb + r;
                if (cc < 8) hst[b][cc] = f2bf(hv);
                if (t == T_STEPS - 1) {
                    if (cc < 8) hs[(size_t)(64 + b) * 512 + jj] = hv;
                    else        cs[(size_t)(64 + b) * 512 + jj] = cn;
                }
            }

            if (lane < 16) {
                int row = wv * 16 + lane;
                stc(h1s + (size_t)t * 32768 + (size_t)wg * 512 + (size_t)row * 8,
                    *(const s16x8*)(&hst[row][0]));
            }

            // out f32 stores: cached path, off the critical chain
            if (cc >= 8) {
                #pragma unroll
                for (int r = 0; r < 4; r++)
                    out[((size_t)(t * 64 + bb + r)) * 512 + jj] = ov[r];
            }
        }
    }
}

// ---- launch -------------------------------------------------------------

extern "C" void kernel_launch(void* const* d_in, const int* in_sizes, int n_in,
                              void* d_out, int out_size, void* d_ws, size_t ws_size,
                              hipStream_t stream) {
    const float* x  = (const float*)d_in[0];
    const float* W0 = (const float*)d_in[1];
    const float* b0 = (const float*)d_in[2];
    const float* W1 = (const float*)d_in[3];
    const float* b1 = (const float*)d_in[4];
    const float* h0 = (const float*)d_in[5];
    const float* c0 = (const float*)d_in[6];
    float* out = (float*)d_out;

    char* ws = (char*)d_ws;
    unsigned short* xb  = (unsigned short*)(ws);                               // 33,554,432 B
    unsigned short* h0s = (unsigned short*)(ws + 33554432);                    // 33,554,432 B
    unsigned short* h1s = (unsigned short*)(ws + 2 * 33554432);                // 33,554,432 B
    unsigned short* WT0 = (unsigned short*)(ws + 3 * 33554432);                //  4,194,304 B
    unsigned short* WT1 = (unsigned short*)(ws + 3 * 33554432 + 4194304);      //  4,194,304 B
    unsigned short* hi0 = (unsigned short*)(ws + 3 * 33554432 + 2 * 4194304);            // 65,536 B
    unsigned short* hi1 = (unsigned short*)(ws + 3 * 33554432 + 2 * 4194304 + 65536);    // 65,536 B

    // canary-fill the h exchange ring (h0s + h1s are contiguous: 64 MB)
    k_fill_canary<<<16384, 256, 0, stream>>>((unsigned long long*)h0s);
    k_conv_bf16<<<8192, 256, 0, stream>>>(x, xb);
    k_transpose_w<<<dim3(64, 32, 2), dim3(32, 8), 0, stream>>>(W0, W1, WT0, WT1);
    k_hinit<<<256, 256, 0, stream>>>(h0, hi0, hi1);

    float* hs = out + 16777216;            // [2][64][512]
    float* cs = hs + 65536;                // [2][64][512]
    k_lstm_fused5<<<128, 256, 0, stream>>>(xb, hi0, hi1, WT0, WT1, b0, b1, c0,
                                           h0s, h1s, out, hs, cs);
}